// Round 7
// baseline (275.420 us; speedup 1.0000x reference)
//
#include <hip/hip_runtime.h>
#include <hip/hip_bf16.h>

// TrendEncoder: histogram (B=4096, S=200 -> 256 bins) + 256-step LSTM (H=64).
// Round 7: two-octet software pipeline on the R5 base (256 thr / 4 waves /
// 16 rows / fp16 h / fused exp2 act -- bit-identical numerics to R5).
//
// Rows split into octets O0 (0-7), O1 (8-15), half a step out of phase.
// Each phase = MFMA(one octet) + activation(other octet, gates already in
// registers from the previous phase) + ONE barrier:
//   P2(t): gates_O1(t)   + act_O0(t) -> write hO0(t+1)
//   P1(t): gates_O0(t+1) + act_O1(t) -> write hO1(t+1)
// The act issue (~290 cyc, trans-dominated) hides the other octet's LDS
// read latency + MFMA chain that R5 paid serially.
//
// A-operand trick: read A rows as h[oct*8 + (m&7)] -> MFMA C rows 8-15 are
// exact duplicates of rows 0-7, so quads 2/3 already hold gate copies:
// redistribution is a v_cndmask select (no shfl). quad q acts local rows
// {(q&1)*4+(q>>1)*2 + 0,1} via regs {(q>>1)*2 + 0,1}.

#define B_S     200
#define B_T     256
#define ROWS    16
#define THREADS 256
#define HS      72    // h row stride (fp16 elems) = 144 B
#define LOG2E   1.4426950408889634f

typedef __attribute__((ext_vector_type(8))) _Float16 half8;
typedef __attribute__((ext_vector_type(4))) float float4_t;

__device__ __forceinline__ float load_f(const void* p, int i, int isb) {
    if (isb) {
        unsigned short u = ((const unsigned short*)p)[i];
        return __uint_as_float(((unsigned int)u) << 16);
    }
    return ((const float*)p)[i];
}

// fused LSTM cell update, identical numerics to R5:
// gates prescaled (i,f,o by -log2e; g by 2*log2e) upstream in W/b.
__device__ __forceinline__ float act_one(float gi, float gf, float gg,
                                         float go, float& c) {
    float A  = __builtin_amdgcn_exp2f(gi);
    float F  = __builtin_amdgcn_exp2f(gf);
    float Bv = __builtin_amdgcn_exp2f(gg);
    float t1    = (1.0f + A) * (Bv + 1.0f);
    float oneF  = 1.0f + F;
    float numer = fmaf(c, t1, oneF * (Bv - 1.0f));
    float denom = oneF * t1;
    c = numer * __builtin_amdgcn_rcpf(denom);
    float D  = __builtin_amdgcn_exp2f(go);
    float cs = fminf(c * (2.0f * LOG2E), 126.0f);   // inf guard
    float E  = __builtin_amdgcn_exp2f(cs);
    return (E - 1.0f) * __builtin_amdgcn_rcpf((1.0f + D) * (E + 1.0f));
}

__global__ __launch_bounds__(THREADS)
void trend_encoder_kernel(const void* __restrict__ time_,
                          const int*  __restrict__ length,
                          const void* __restrict__ ptime_,
                          const void* __restrict__ wih_,
                          const void* __restrict__ whh_,
                          const void* __restrict__ bih_,
                          const void* __restrict__ bhh_,
                          void* __restrict__ out_) {
    __shared__ __align__(16) float x_t[B_T * ROWS];       // [t][row], 16 KB
    __shared__ __align__(16) _Float16 h_sh[ROWS * HS];    // single buffer
    __shared__ int flag_sh;

    const int tid  = threadIdx.x;
    const int wv   = tid >> 6;        // wave 0..3 -> col-group 16*wv
    const int lane = tid & 63;
    const int m    = lane & 15;
    const int quad = lane >> 4;
    const int b0   = blockIdx.x * ROWS;

    // ---- dtype probe (wave 0): W_ih ~ U(-0.125,0.125); f32 reinterpreted as
    // bf16 words goes far out of range with overwhelming probability.
    if (tid < 64) {
        unsigned short u = ((const unsigned short*)wih_)[tid];
        float v = __uint_as_float(((unsigned int)u) << 16);
        int bad = !(v > -0.2f && v < 0.2f);
        unsigned long long bm = __ballot(bad);
        if (lane == 0) flag_sh = (bm == 0ULL) ? 1 : 0;
    }
    for (int i = tid; i < B_T * ROWS; i += THREADS) x_t[i] = 0.0f;
    for (int i = tid; i < ROWS * HS; i += THREADS) h_sh[i] = (_Float16)0.0f;
    __syncthreads();
    const int isb = flag_sh;

    // ---- histogram: pos = trunc((pt - t)*0.25), add at bin 255-pos (transposed)
    for (int e = tid; e < ROWS * B_S; e += THREADS) {
        int row  = e / B_S;
        int s    = e - row * B_S;
        int grow = b0 + row;
        if (s < length[grow]) {
            float pt = load_f(ptime_, grow, isb);
            float tv = load_f(time_, grow * B_S + s, isb);
            int pos = (int)((pt - tv) * 0.25f);
            if (pos >= 0 && pos < B_T)
                atomicAdd(&x_t[(B_T - 1 - pos) * ROWS + row], 1.0f);
        }
    }

    // ---- resident weights (fp16, gate-prescaled). tile tt = gate (i,f,g,o),
    // col n = 16wv + 64tt + m.  B-frag: n = lane&15, k = 32c + 8*quad + j.
    const float gsc[4] = {-LOG2E, -LOG2E, 2.0f * LOG2E, -LOG2E};
    half8 bw[4][2];
    float wihv[4], biasv[4];
    #pragma unroll
    for (int tt = 0; tt < 4; ++tt) {
        int n = 16 * wv + 64 * tt + m;
        float s = gsc[tt];
        wihv[tt]  = load_f(wih_, n, isb) * s;
        biasv[tt] = (load_f(bih_, n, isb) + load_f(bhh_, n, isb)) * s;
        #pragma unroll
        for (int c = 0; c < 2; ++c) {
            half8 v;
            #pragma unroll
            for (int j = 0; j < 8; ++j)
                v[j] = (_Float16)(load_f(whh_, n * 64 + 32 * c + 8 * quad + j, isb) * s);
            bw[tt][c] = v;
        }
    }

    const int aoff = (m & 7) * HS + 8 * quad;   // A-frag base, octet 0
    const int kcol = 16 * wv + m;               // owned unit column
    const int lr0  = (quad & 1) * 4 + (quad >> 1) * 2;  // first owned local row
    const int xq   = (quad & 1) * 4;            // x row sub-group
    const bool loq = (quad < 2);                // own regs {0,1} vs {2,3}

    float c0[2] = {0.f, 0.f}, c1[2] = {0.f, 0.f};
    float h0[2] = {0.f, 0.f}, h1[2] = {0.f, 0.f};
    float4_t accO0[4], accO1[4];

    // gates for octet `oct` at step t (reads h_sh + x_t)
    auto gates = [&](float4_t (&acc)[4], int oct, int t) {
        const _Float16* hp = &h_sh[oct * 8 * HS + aoff];
        half8 a0 = *(const half8*)hp;
        half8 a1 = *(const half8*)(hp + 32);
        float4_t xv = *(const float4_t*)&x_t[t * ROWS + oct * 8 + xq];
        #pragma unroll
        for (int tt = 0; tt < 4; ++tt) {
            float4_t c;
            #pragma unroll
            for (int r = 0; r < 4; ++r) c[r] = fmaf(xv[r], wihv[tt], biasv[tt]);
            c = __builtin_amdgcn_mfma_f32_16x16x32_f16(a0, bw[tt][0], c, 0, 0, 0);
            c = __builtin_amdgcn_mfma_f32_16x16x32_f16(a1, bw[tt][1], c, 0, 0, 0);
            acc[tt] = c;
        }
    };
    // activation of the 2 owned units of octet `oct` (+ optional h store)
    auto act2 = [&](float4_t (&acc)[4], float (&cc)[2], float (&hh)[2],
                    int oct, bool store) {
        #pragma unroll
        for (int k = 0; k < 2; ++k) {
            float gi = loq ? acc[0][k] : acc[0][2 + k];
            float gf = loq ? acc[1][k] : acc[1][2 + k];
            float gg = loq ? acc[2][k] : acc[2][2 + k];
            float go = loq ? acc[3][k] : acc[3][2 + k];
            hh[k] = act_one(gi, gf, gg, go, cc[k]);
            if (store)
                h_sh[(oct * 8 + lr0 + k) * HS + kcol] = (_Float16)hh[k];
        }
    };

    __syncthreads();   // histogram + h init + weights visible

    // ---- prologue: gates_O0(0) (h = 0)
    gates(accO0, 0, 0);
    __syncthreads();   // all prologue reads of hO0 done before first write

    // ---- pipelined main loop: 2 phases per step, 1 barrier each
    for (int t = 0; t < B_T - 1; ++t) {
        gates(accO1, 1, t);                 // reads hO1(t)
        act2(accO0, c0, h0, 0, true);       // writes hO0(t+1)
        __syncthreads();
        gates(accO0, 0, t + 1);             // reads hO0(t+1)
        act2(accO1, c1, h1, 1, true);       // writes hO1(t+1)
        __syncthreads();
    }
    // ---- tail: t = 255
    gates(accO1, 1, B_T - 1);               // reads hO1(255)
    act2(accO0, c0, h0, 0, false);          // final h, octet 0
    act2(accO1, c1, h1, 1, false);          // final h, octet 1

    // ---- epilogue: 4 owned outputs (2 per octet)
    #pragma unroll
    for (int k = 0; k < 2; ++k) {
        int o0 = (b0 + lr0 + k) * 64 + kcol;
        int o1 = (b0 + 8 + lr0 + k) * 64 + kcol;
        if (isb) {
            ((__hip_bfloat16*)out_)[o0] = __float2bfloat16(h0[k]);
            ((__hip_bfloat16*)out_)[o1] = __float2bfloat16(h1[k]);
        } else {
            ((float*)out_)[o0] = h0[k];
            ((float*)out_)[o1] = h1[k];
        }
    }
}

extern "C" void kernel_launch(void* const* d_in, const int* in_sizes, int n_in,
                              void* d_out, int out_size, void* d_ws, size_t ws_size,
                              hipStream_t stream) {
    const void* time_  = d_in[0];
    const int*  length = (const int*)d_in[1];
    const void* ptime  = d_in[2];
    const void* wih    = d_in[3];
    const void* whh    = d_in[4];
    const void* bih    = d_in[5];
    const void* bhh    = d_in[6];

    const int B = in_sizes[1];   // 4096
    trend_encoder_kernel<<<dim3(B / ROWS), dim3(THREADS), 0, stream>>>(
        time_, length, ptime, wih, whh, bih, bhh, d_out);
}

// Round 8
// 204.468 us; speedup vs baseline: 1.3470x; 1.3470x over previous
//
#include <hip/hip_runtime.h>
#include <hip/hip_bf16.h>

// TrendEncoder: histogram (B=4096, S=200 -> 256 bins) + 256-step LSTM (H=64).
// Round 8: R5 math (fp16 h, fused exp2/rcp act, gate-prescaled weights) on
// R4's concurrency structure: ROWS=8, 256 threads, grid 512 -> 2 independent
// blocks per CU (2 waves/SIMD with DECOUPLED barriers) so one block's
// activation issue hides the other block's LDS/MFMA/barrier stall.
//
// Duplicate-row A trick (verified in R7): A-frag reads h[(m&7)] so MFMA C
// rows 8-15 duplicate rows 0-7 -> quads 2/3 hold gate copies; activation
// redistribution is a v_cndmask select (no shfl). quad q owns local rows
// {(q&1)*4 + (q>>1)*2 + 0,1} via regs {0,1} (q<2) or {2,3} (q>=2).
// Numerics bit-identical to R5.

#define B_S     200
#define B_T     256
#define ROWS    8
#define THREADS 256
#define HS      72    // h row stride (fp16 elems) = 144 B
#define LOG2E   1.4426950408889634f

typedef __attribute__((ext_vector_type(8))) _Float16 half8;
typedef __attribute__((ext_vector_type(4))) float float4_t;

__device__ __forceinline__ float load_f(const void* p, int i, int isb) {
    if (isb) {
        unsigned short u = ((const unsigned short*)p)[i];
        return __uint_as_float(((unsigned int)u) << 16);
    }
    return ((const float*)p)[i];
}

// fused LSTM cell update (identical numerics to R5): gates prescaled
// (i,f,o by -log2e; g by 2*log2e) upstream in W/b.
__device__ __forceinline__ float act_one(float gi, float gf, float gg,
                                         float go, float& c) {
    float A  = __builtin_amdgcn_exp2f(gi);
    float F  = __builtin_amdgcn_exp2f(gf);
    float Bv = __builtin_amdgcn_exp2f(gg);
    float t1    = (1.0f + A) * (Bv + 1.0f);
    float oneF  = 1.0f + F;
    float numer = fmaf(c, t1, oneF * (Bv - 1.0f));
    float denom = oneF * t1;
    c = numer * __builtin_amdgcn_rcpf(denom);
    float D  = __builtin_amdgcn_exp2f(go);
    float cs = fminf(c * (2.0f * LOG2E), 126.0f);   // inf guard
    float E  = __builtin_amdgcn_exp2f(cs);
    return (E - 1.0f) * __builtin_amdgcn_rcpf((1.0f + D) * (E + 1.0f));
}

__global__ __launch_bounds__(THREADS, 2)
void trend_encoder_kernel(const void* __restrict__ time_,
                          const int*  __restrict__ length,
                          const void* __restrict__ ptime_,
                          const void* __restrict__ wih_,
                          const void* __restrict__ whh_,
                          const void* __restrict__ bih_,
                          const void* __restrict__ bhh_,
                          void* __restrict__ out_) {
    __shared__ __align__(16) float x_t[B_T * ROWS];          // [t][row], 8 KB
    __shared__ __align__(16) _Float16 h_sh[2][ROWS * HS];    // double-buffered
    __shared__ int flag_sh;

    const int tid  = threadIdx.x;
    const int wv   = tid >> 6;        // wave 0..3 -> col-group 16*wv
    const int lane = tid & 63;
    const int m    = lane & 15;
    const int quad = lane >> 4;
    const int b0   = blockIdx.x * ROWS;

    // ---- dtype probe (wave 0): W_ih ~ U(-0.125,0.125); f32 reinterpreted as
    // bf16 words goes far out of range with overwhelming probability.
    if (tid < 64) {
        unsigned short u = ((const unsigned short*)wih_)[tid];
        float v = __uint_as_float(((unsigned int)u) << 16);
        int bad = !(v > -0.2f && v < 0.2f);
        unsigned long long bm = __ballot(bad);
        if (lane == 0) flag_sh = (bm == 0ULL) ? 1 : 0;
    }
    for (int i = tid; i < B_T * ROWS; i += THREADS) x_t[i] = 0.0f;
    for (int i = tid; i < 2 * ROWS * HS; i += THREADS)
        ((_Float16*)h_sh)[i] = (_Float16)0.0f;
    __syncthreads();
    const int isb = flag_sh;

    // ---- histogram: pos = trunc((pt - t)*0.25), add at bin 255-pos (transposed)
    for (int e = tid; e < ROWS * B_S; e += THREADS) {
        int row  = e / B_S;
        int s    = e - row * B_S;
        int grow = b0 + row;
        if (s < length[grow]) {
            float pt = load_f(ptime_, grow, isb);
            float tv = load_f(time_, grow * B_S + s, isb);
            int pos = (int)((pt - tv) * 0.25f);
            if (pos >= 0 && pos < B_T)
                atomicAdd(&x_t[(B_T - 1 - pos) * ROWS + row], 1.0f);
        }
    }

    // ---- resident weights (fp16, gate-prescaled). tile tt = gate (i,f,g,o),
    // col n = 16wv + 64tt + m.  B-frag: n = lane&15, k = 32c + 8*quad + j.
    const float gsc[4] = {-LOG2E, -LOG2E, 2.0f * LOG2E, -LOG2E};
    half8 bw[4][2];
    float wihv[4], biasv[4];
    #pragma unroll
    for (int tt = 0; tt < 4; ++tt) {
        int n = 16 * wv + 64 * tt + m;
        float s = gsc[tt];
        wihv[tt]  = load_f(wih_, n, isb) * s;
        biasv[tt] = (load_f(bih_, n, isb) + load_f(bhh_, n, isb)) * s;
        #pragma unroll
        for (int c = 0; c < 2; ++c) {
            half8 v;
            #pragma unroll
            for (int j = 0; j < 8; ++j)
                v[j] = (_Float16)(load_f(whh_, n * 64 + 32 * c + 8 * quad + j, isb) * s);
            bw[tt][c] = v;
        }
    }

    const int aoff = (m & 7) * HS + 8 * quad;   // A-frag base (duplicate rows)
    const int kcol = 16 * wv + m;               // owned unit column
    const int lr0  = (quad & 1) * 4 + (quad >> 1) * 2;  // first owned local row
    const int xq   = (quad & 1) * 4;            // x row sub-group
    const bool loq = (quad < 2);                // own regs {0,1} vs {2,3}
    float c2[2] = {0.f, 0.f};
    float h2[2] = {0.f, 0.f};
    __syncthreads();   // histogram + h init + weights visible

    for (int t = 0; t < B_T; ++t) {
        const int p = t & 1;
        const _Float16* hh = h_sh[p];
        half8 a0 = *(const half8*)&hh[aoff];
        half8 a1 = *(const half8*)&hh[aoff + 32];
        float4_t xv = *(const float4_t*)&x_t[t * ROWS + xq];

        float4_t acc[4];
        #pragma unroll
        for (int tt = 0; tt < 4; ++tt) {
            float4_t c;
            #pragma unroll
            for (int r = 0; r < 4; ++r) c[r] = fmaf(xv[r], wihv[tt], biasv[tt]);
            c = __builtin_amdgcn_mfma_f32_16x16x32_f16(a0, bw[tt][0], c, 0, 0, 0);
            c = __builtin_amdgcn_mfma_f32_16x16x32_f16(a1, bw[tt][1], c, 0, 0, 0);
            acc[tt] = c;
        }

        // fused in-lane activation: 2 units (rows lr0, lr0+1; col kcol);
        // quads 2/3 use duplicate regs 2/3 (v_cndmask select, no shfl)
        _Float16* wb = h_sh[p ^ 1];
        #pragma unroll
        for (int k = 0; k < 2; ++k) {
            float gi = loq ? acc[0][k] : acc[0][2 + k];
            float gf = loq ? acc[1][k] : acc[1][2 + k];
            float gg = loq ? acc[2][k] : acc[2][2 + k];
            float go = loq ? acc[3][k] : acc[3][2 + k];
            h2[k] = act_one(gi, gf, gg, go, c2[k]);
            wb[(lr0 + k) * HS + kcol] = (_Float16)h2[k];
        }
        __syncthreads();   // the only barrier per step
    }

    // ---- epilogue: final h of the 2 owned units
    #pragma unroll
    for (int k = 0; k < 2; ++k) {
        int o = (b0 + lr0 + k) * 64 + kcol;
        if (isb) ((__hip_bfloat16*)out_)[o] = __float2bfloat16(h2[k]);
        else     ((float*)out_)[o] = h2[k];
    }
}

extern "C" void kernel_launch(void* const* d_in, const int* in_sizes, int n_in,
                              void* d_out, int out_size, void* d_ws, size_t ws_size,
                              hipStream_t stream) {
    const void* time_  = d_in[0];
    const int*  length = (const int*)d_in[1];
    const void* ptime  = d_in[2];
    const void* wih    = d_in[3];
    const void* whh    = d_in[4];
    const void* bih    = d_in[5];
    const void* bhh    = d_in[6];

    const int B = in_sizes[1];   // 4096
    trend_encoder_kernel<<<dim3(B / ROWS), dim3(THREADS), 0, stream>>>(
        time_, length, ptime, wih, whh, bih, bhh, d_out);
}

// Round 9
// 202.352 us; speedup vs baseline: 1.3611x; 1.0105x over previous
//
#include <hip/hip_runtime.h>
#include <hip/hip_bf16.h>

// TrendEncoder: histogram (B=4096, S=200 -> 256 bins) + 256-step LSTM (H=64).
// Round 9: R8 (2 independent 8-row blocks/CU, fp16 h, fused exp2 act) plus an
// explicit PHASE STAGGER: one block of each co-resident pair sleeps ~450 cyc
// before entering the LSTM loop. R8's counters showed both co-resident blocks
// issue (VALUBusy 54% = 810 cyc/SIMD) but stall together (~690 cyc) -- they
// phase-lock because identical periodic structures + shared quarter-rate
// trans pipe make in-phase execution self-stabilizing. The one-time offset
// flips them into the anti-phase fixed point where block X's ~500-cyc act
// issue fills block Y's ~600-cyc LDS/MFMA/barrier stall.
// Pair parity keyed on (blockIdx ^ blockIdx>>8) & 1 so it differs whether the
// CU pairing is (b, b+1) or (b, b+256).

#define B_S     200
#define B_T     256
#define ROWS    8
#define THREADS 256
#define HS      72    // h row stride (fp16 elems) = 144 B
#define LOG2E   1.4426950408889634f

typedef __attribute__((ext_vector_type(8))) _Float16 half8;
typedef __attribute__((ext_vector_type(4))) float float4_t;

__device__ __forceinline__ float load_f(const void* p, int i, int isb) {
    if (isb) {
        unsigned short u = ((const unsigned short*)p)[i];
        return __uint_as_float(((unsigned int)u) << 16);
    }
    return ((const float*)p)[i];
}

// fused LSTM cell update (identical numerics to R5): gates prescaled
// (i,f,o by -log2e; g by 2*log2e) upstream in W/b.
__device__ __forceinline__ float act_one(float gi, float gf, float gg,
                                         float go, float& c) {
    float A  = __builtin_amdgcn_exp2f(gi);
    float F  = __builtin_amdgcn_exp2f(gf);
    float Bv = __builtin_amdgcn_exp2f(gg);
    float t1    = (1.0f + A) * (Bv + 1.0f);
    float oneF  = 1.0f + F;
    float numer = fmaf(c, t1, oneF * (Bv - 1.0f));
    float denom = oneF * t1;
    c = numer * __builtin_amdgcn_rcpf(denom);
    float D  = __builtin_amdgcn_exp2f(go);
    float cs = fminf(c * (2.0f * LOG2E), 126.0f);   // inf guard
    float E  = __builtin_amdgcn_exp2f(cs);
    return (E - 1.0f) * __builtin_amdgcn_rcpf((1.0f + D) * (E + 1.0f));
}

__global__ __launch_bounds__(THREADS, 2)
void trend_encoder_kernel(const void* __restrict__ time_,
                          const int*  __restrict__ length,
                          const void* __restrict__ ptime_,
                          const void* __restrict__ wih_,
                          const void* __restrict__ whh_,
                          const void* __restrict__ bih_,
                          const void* __restrict__ bhh_,
                          void* __restrict__ out_) {
    __shared__ __align__(16) float x_t[B_T * ROWS];          // [t][row], 8 KB
    __shared__ __align__(16) _Float16 h_sh[2][ROWS * HS];    // double-buffered
    __shared__ int flag_sh;

    const int tid  = threadIdx.x;
    const int wv   = tid >> 6;        // wave 0..3 -> col-group 16*wv
    const int lane = tid & 63;
    const int m    = lane & 15;
    const int quad = lane >> 4;
    const int b0   = blockIdx.x * ROWS;

    // ---- dtype probe (wave 0): W_ih ~ U(-0.125,0.125); f32 reinterpreted as
    // bf16 words goes far out of range with overwhelming probability.
    if (tid < 64) {
        unsigned short u = ((const unsigned short*)wih_)[tid];
        float v = __uint_as_float(((unsigned int)u) << 16);
        int bad = !(v > -0.2f && v < 0.2f);
        unsigned long long bm = __ballot(bad);
        if (lane == 0) flag_sh = (bm == 0ULL) ? 1 : 0;
    }
    for (int i = tid; i < B_T * ROWS; i += THREADS) x_t[i] = 0.0f;
    for (int i = tid; i < 2 * ROWS * HS; i += THREADS)
        ((_Float16*)h_sh)[i] = (_Float16)0.0f;
    __syncthreads();
    const int isb = flag_sh;

    // ---- histogram: pos = trunc((pt - t)*0.25), add at bin 255-pos (transposed)
    for (int e = tid; e < ROWS * B_S; e += THREADS) {
        int row  = e / B_S;
        int s    = e - row * B_S;
        int grow = b0 + row;
        if (s < length[grow]) {
            float pt = load_f(ptime_, grow, isb);
            float tv = load_f(time_, grow * B_S + s, isb);
            int pos = (int)((pt - tv) * 0.25f);
            if (pos >= 0 && pos < B_T)
                atomicAdd(&x_t[(B_T - 1 - pos) * ROWS + row], 1.0f);
        }
    }

    // ---- resident weights (fp16, gate-prescaled). tile tt = gate (i,f,g,o),
    // col n = 16wv + 64tt + m.  B-frag: n = lane&15, k = 32c + 8*quad + j.
    const float gsc[4] = {-LOG2E, -LOG2E, 2.0f * LOG2E, -LOG2E};
    half8 bw[4][2];
    float wihv[4], biasv[4];
    #pragma unroll
    for (int tt = 0; tt < 4; ++tt) {
        int n = 16 * wv + 64 * tt + m;
        float s = gsc[tt];
        wihv[tt]  = load_f(wih_, n, isb) * s;
        biasv[tt] = (load_f(bih_, n, isb) + load_f(bhh_, n, isb)) * s;
        #pragma unroll
        for (int c = 0; c < 2; ++c) {
            half8 v;
            #pragma unroll
            for (int j = 0; j < 8; ++j)
                v[j] = (_Float16)(load_f(whh_, n * 64 + 32 * c + 8 * quad + j, isb) * s);
            bw[tt][c] = v;
        }
    }

    const int aoff = (m & 7) * HS + 8 * quad;   // A-frag base (duplicate rows)
    const int kcol = 16 * wv + m;               // owned unit column
    const int lr0  = (quad & 1) * 4 + (quad >> 1) * 2;  // first owned local row
    const int xq   = (quad & 1) * 4;            // x row sub-group
    const bool loq = (quad < 2);                // own regs {0,1} vs {2,3}
    float c2[2] = {0.f, 0.f};
    float h2[2] = {0.f, 0.f};
    __syncthreads();   // histogram + h init + weights visible

    // ---- phase stagger: one block of each co-resident pair delays ~450 cyc
    // so the pair settles into the anti-phase fixed point (act issue of one
    // fills the stall of the other) instead of the in-phase one.
    if ((blockIdx.x ^ (blockIdx.x >> 8)) & 1) {
        __builtin_amdgcn_s_sleep(7);   // ~448 cycles
    }

    for (int t = 0; t < B_T; ++t) {
        const int p = t & 1;
        const _Float16* hh = h_sh[p];
        half8 a0 = *(const half8*)&hh[aoff];
        half8 a1 = *(const half8*)&hh[aoff + 32];
        float4_t xv = *(const float4_t*)&x_t[t * ROWS + xq];

        float4_t acc[4];
        #pragma unroll
        for (int tt = 0; tt < 4; ++tt) {
            float4_t c;
            #pragma unroll
            for (int r = 0; r < 4; ++r) c[r] = fmaf(xv[r], wihv[tt], biasv[tt]);
            c = __builtin_amdgcn_mfma_f32_16x16x32_f16(a0, bw[tt][0], c, 0, 0, 0);
            c = __builtin_amdgcn_mfma_f32_16x16x32_f16(a1, bw[tt][1], c, 0, 0, 0);
            acc[tt] = c;
        }

        // fused in-lane activation: 2 units (rows lr0, lr0+1; col kcol);
        // quads 2/3 use duplicate regs 2/3 (v_cndmask select, no shfl)
        _Float16* wb = h_sh[p ^ 1];
        #pragma unroll
        for (int k = 0; k < 2; ++k) {
            float gi = loq ? acc[0][k] : acc[0][2 + k];
            float gf = loq ? acc[1][k] : acc[1][2 + k];
            float gg = loq ? acc[2][k] : acc[2][2 + k];
            float go = loq ? acc[3][k] : acc[3][2 + k];
            h2[k] = act_one(gi, gf, gg, go, c2[k]);
            wb[(lr0 + k) * HS + kcol] = (_Float16)h2[k];
        }
        __syncthreads();   // the only barrier per step
    }

    // ---- epilogue: final h of the 2 owned units
    #pragma unroll
    for (int k = 0; k < 2; ++k) {
        int o = (b0 + lr0 + k) * 64 + kcol;
        if (isb) ((__hip_bfloat16*)out_)[o] = __float2bfloat16(h2[k]);
        else     ((float*)out_)[o] = h2[k];
    }
}

extern "C" void kernel_launch(void* const* d_in, const int* in_sizes, int n_in,
                              void* d_out, int out_size, void* d_ws, size_t ws_size,
                              hipStream_t stream) {
    const void* time_  = d_in[0];
    const int*  length = (const int*)d_in[1];
    const void* ptime  = d_in[2];
    const void* wih    = d_in[3];
    const void* whh    = d_in[4];
    const void* bih    = d_in[5];
    const void* bhh    = d_in[6];

    const int B = in_sizes[1];   // 4096
    trend_encoder_kernel<<<dim3(B / ROWS), dim3(THREADS), 0, stream>>>(
        time_, length, ptime, wih, whh, bih, bhh, d_out);
}